// Round 1
// baseline (1428.594 us; speedup 1.0000x reference)
//
#include <hip/hip_runtime.h>
#include <math.h>

#define B_ 4
#define L_ 2048
#define D_ 2048
#define M_ 64
#define R_ 128
#define NTOK (B_*L_)
#define SCALE_ 0.125f

// ---------------- 1. causal depthwise conv (W=4) + silu ----------------
__global__ __launch_bounds__(256) void k_conv(const float* __restrict__ x,
    const float* __restrict__ cw, const float* __restrict__ cb,
    float* __restrict__ shift)
{
    size_t idx = (size_t)blockIdx.x * 256 + threadIdx.x;
    int d = (int)(idx % D_);
    size_t n = idx / D_;
    int l = (int)(n % L_);
    float y = cb[d];
    const float* wp = cw + (size_t)d * 4;
#pragma unroll
    for (int i = 0; i < 4; i++) {
        int ll = l - 3 + i;
        if (ll >= 0) y = fmaf(x[idx + (size_t)(i - 3) * D_], wp[i], y);
    }
    shift[idx] = y / (1.f + expf(-y));
}

// ---------------- fp32 NT GEMM: out[n, jo+j] = A[n,:K] . Wm[j,:K] ----------------
// mode 0: plain store. mode 1: out = sigmoid(acc + bias[j]) * xmul[n*ldo + j]
#define BN 64
#define BJ 64
#define BK 16
#define LDP 68

__global__ __launch_bounds__(256) void k_gemm_nt(
    const float* __restrict__ A, const float* __restrict__ Wm,
    float* __restrict__ out, int K, int ldo, int jo,
    int mode, const float* __restrict__ bias, const float* __restrict__ xmul)
{
    __shared__ float As[BK][LDP];
    __shared__ float Ws[BK][LDP];
    int tid = threadIdx.x;
    int n0 = blockIdx.x * BN;
    int j0 = blockIdx.y * BJ;
    int lr = tid >> 2;           // 0..63 tile row
    int lk = (tid & 3) << 2;     // 0,4,8,12 k offset
    int ti = tid >> 4;           // 0..15 output row group
    int tj = tid & 15;           // 0..15 output col group

    float acc[4][4];
#pragma unroll
    for (int i = 0; i < 4; i++)
#pragma unroll
        for (int j = 0; j < 4; j++) acc[i][j] = 0.f;

    for (int k0 = 0; k0 < K; k0 += BK) {
        float4 av = *(const float4*)&A[(size_t)(n0 + lr) * K + k0 + lk];
        float4 wv = *(const float4*)&Wm[(size_t)(j0 + lr) * K + k0 + lk];
        __syncthreads();
        As[lk + 0][lr] = av.x; As[lk + 1][lr] = av.y;
        As[lk + 2][lr] = av.z; As[lk + 3][lr] = av.w;
        Ws[lk + 0][lr] = wv.x; Ws[lk + 1][lr] = wv.y;
        Ws[lk + 2][lr] = wv.z; Ws[lk + 3][lr] = wv.w;
        __syncthreads();
#pragma unroll
        for (int kk = 0; kk < BK; kk++) {
            float4 a = *(const float4*)&As[kk][ti << 2];
            float4 w = *(const float4*)&Ws[kk][tj << 2];
            float aa[4] = {a.x, a.y, a.z, a.w};
            float ww[4] = {w.x, w.y, w.z, w.w};
#pragma unroll
            for (int i = 0; i < 4; i++)
#pragma unroll
                for (int j = 0; j < 4; j++)
                    acc[i][j] = fmaf(aa[i], ww[j], acc[i][j]);
        }
    }

#pragma unroll
    for (int i = 0; i < 4; i++) {
        int n = n0 + (ti << 2) + i;
        int jg = j0 + (tj << 2);
        float vv[4];
#pragma unroll
        for (int j = 0; j < 4; j++) {
            float val = acc[i][j];
            if (mode == 1) {
                val += bias[jg + j];
                val = 1.f / (1.f + expf(-val));
                val *= xmul[(size_t)n * ldo + jo + jg + j];
            }
            vv[j] = val;
        }
        float4 v = {vv[0], vv[1], vv[2], vv[3]};
        *(float4*)&out[(size_t)n * ldo + jo + jg] = v;
    }
}

// ---------------- 5. per-token gate prep ----------------
__global__ __launch_bounds__(64) void k_prep(const float* __restrict__ rkmg,
    const float* __restrict__ mb, float* __restrict__ Rb,
    float* __restrict__ Kb, float* __restrict__ Gb)
{
    int n = blockIdx.x;
    int m = threadIdx.x;
    const float* row = rkmg + (size_t)n * 256;
    float r   = row[m];
    float k   = row[64 + m];
    float mg1 = row[128 + m] + mb[m];
    float mg2 = row[192 + m] + mb[64 + m];
    float sel = (mg1 > 20.f) ? mg1 : log1pf(expf(mg1));
    float tau = 1.f / (1.f + expf(-mg2));
    float it  = expf(tau * logf(sel));        // sel^tau, sel>0 (softplus)
    float g   = -sel * tau;
    float s2  = k * k;
#pragma unroll
    for (int off = 32; off >= 1; off >>= 1) s2 += __shfl_xor(s2, off, 64);
    float kn = k / fmaxf(sqrtf(s2), 1e-12f);
    size_t o = (size_t)n * 64 + m;
    Rb[o] = r;
    Kb[o] = kn * it;
    Gb[o] = expf(g);
}

// ---------------- 6. sequential recurrence ----------------
// wave = 64 lanes = 4 m-groups x 16 d-columns; S[16] per lane in VGPRs.
struct TSet { float4 r[4], k[4], g[4]; float uv, sv; };

__device__ __forceinline__ void load_set(TSet& s,
    const float* __restrict__ Rp, const float* __restrict__ Kp,
    const float* __restrict__ Gp, const float* __restrict__ up,
    const float* __restrict__ sp, int t)
{
    const float4* r4 = (const float4*)(Rp + (size_t)t * 64);
    const float4* k4 = (const float4*)(Kp + (size_t)t * 64);
    const float4* g4 = (const float4*)(Gp + (size_t)t * 64);
#pragma unroll
    for (int q = 0; q < 4; q++) { s.r[q] = r4[q]; s.k[q] = k4[q]; s.g[q] = g4[q]; }
    s.uv = up[(size_t)t * D_];
    s.sv = sp[(size_t)t * D_];
}

__device__ __forceinline__ void step_t(const TSet& c, float S[16], float rwv,
    float* __restrict__ op, int t, int lane)
{
    float p0 = 0.f, p1 = 0.f, p2 = 0.f, p3 = 0.f;
#pragma unroll
    for (int q = 0; q < 4; q++) {
        S[4*q+0] = fmaf(c.g[q].x, S[4*q+0], c.k[q].x * c.uv); p0 = fmaf(c.r[q].x, S[4*q+0], p0);
        S[4*q+1] = fmaf(c.g[q].y, S[4*q+1], c.k[q].y * c.uv); p1 = fmaf(c.r[q].y, S[4*q+1], p1);
        S[4*q+2] = fmaf(c.g[q].z, S[4*q+2], c.k[q].z * c.uv); p2 = fmaf(c.r[q].z, S[4*q+2], p2);
        S[4*q+3] = fmaf(c.g[q].w, S[4*q+3], c.k[q].w * c.uv); p3 = fmaf(c.r[q].w, S[4*q+3], p3);
    }
    float part = (p0 + p1) + (p2 + p3);
    part += __shfl_xor(part, 16, 64);
    part += __shfl_xor(part, 32, 64);
    if (lane < 16)
        op[(size_t)t * D_] = SCALE_ * part + c.sv * rwv;
}

__global__ __launch_bounds__(64) void k_rec(const float* __restrict__ Rb,
    const float* __restrict__ Kb, const float* __restrict__ Gb,
    const float* __restrict__ u, const float* __restrict__ shift,
    const float* __restrict__ rw, float* __restrict__ out)
{
    int wid = blockIdx.x;            // 0..511
    int b = wid >> 7;
    int d0 = (wid & 127) << 4;
    int lane = threadIdx.x;
    int mg = lane >> 4;
    int di = lane & 15;
    int d = d0 + di;

    float S[16];
#pragma unroll
    for (int i = 0; i < 16; i++) S[i] = 0.f;
    float rwv = rw[d];

    size_t base = (size_t)b * L_ * D_ + d;
    const float* up = u + base;
    const float* sp = shift + base;
    float* op = out + base;
    size_t pbase = (size_t)b * L_ * 64 + mg * 16;
    const float* Rp = Rb + pbase;
    const float* Kp = Kb + pbase;
    const float* Gp = Gb + pbase;

    TSet s0, s1;
    load_set(s0, Rp, Kp, Gp, up, sp, 0);
    for (int t = 0; t < L_; t += 2) {
        load_set(s1, Rp, Kp, Gp, up, sp, t + 1);
        step_t(s0, S, rwv, op, t, lane);
        if (t + 2 < L_) load_set(s0, Rp, Kp, Gp, up, sp, t + 2);
        step_t(s1, S, rwv, op, t + 1, lane);
    }
}

// ---------------- launcher ----------------
extern "C" void kernel_launch(void* const* d_in, const int* in_sizes, int n_in,
                              void* d_out, int out_size, void* d_ws, size_t ws_size,
                              hipStream_t stream)
{
    const float* x   = (const float*)d_in[0];
    const float* cw  = (const float*)d_in[1];
    const float* cb  = (const float*)d_in[2];
    const float* ipw = (const float*)d_in[3];  // (128, 2048)
    const float* w0  = (const float*)d_in[4];  // (128, 2048)
    const float* w1  = (const float*)d_in[5];  // (2048, 128)
    const float* b1  = (const float*)d_in[6];
    const float* mw  = (const float*)d_in[7];  // (128, 2048)
    const float* mb  = (const float*)d_in[8];
    const float* rw  = (const float*)d_in[9];
    float* out = (float*)d_out;

    float* ws    = (float*)d_ws;
    float* shift = ws;                              // 16,777,216 f
    float* u     = shift + (size_t)NTOK * D_;       // 16,777,216 f
    float* rkmg  = u + (size_t)NTOK * D_;           //  2,097,152 f
    float* t1    = rkmg + (size_t)NTOK * 256;       //  1,048,576 f
    float* Rb    = t1 + (size_t)NTOK * R_;          //    524,288 f
    float* Kb    = Rb + (size_t)NTOK * 64;
    float* Gb    = Kb + (size_t)NTOK * 64;

    // 1. shift = silu(causal_conv(x))
    k_conv<<<(NTOK * (size_t)D_) / 256, 256, 0, stream>>>(x, cw, cb, shift);

    // 2. rkmg[:, :128] = shift @ in_proj_w^T ; rkmg[:, 128:] = shift @ mem_gate_w^T
    dim3 g2(NTOK / BN, 128 / BJ);
    k_gemm_nt<<<g2, 256, 0, stream>>>(shift, ipw, rkmg, D_, 256, 0,   0, nullptr, nullptr);
    k_gemm_nt<<<g2, 256, 0, stream>>>(shift, mw,  rkmg, D_, 256, 128, 0, nullptr, nullptr);

    // 3. t1 = x @ ch_gate_w0^T
    k_gemm_nt<<<dim3(NTOK / BN, R_ / BJ), 256, 0, stream>>>(x, w0, t1, D_, R_, 0, 0, nullptr, nullptr);

    // 4. u = sigmoid(t1 @ ch_gate_w1^T + b1) * x
    k_gemm_nt<<<dim3(NTOK / BN, D_ / BJ), 256, 0, stream>>>(t1, w1, u, R_, D_, 0, 1, b1, x);

    // 5. gate prep: r, k_hat*it_gate, exp(g)
    k_prep<<<NTOK, 64, 0, stream>>>(rkmg, mb, Rb, Kb, Gb);

    // 6. recurrence + residual epilogue
    k_rec<<<512, 64, 0, stream>>>(Rb, Kb, Gb, u, shift, rw, out);
}

// Round 2
// 1150.457 us; speedup vs baseline: 1.2418x; 1.2418x over previous
//
#include <hip/hip_runtime.h>
#include <math.h>

#define B_ 4
#define L_ 2048
#define D_ 2048
#define M_ 64
#define R_ 128
#define NTOK (B_*L_)
#define SCALE_ 0.125f

// ---------------- 1. causal depthwise conv (W=4) + silu ----------------
__global__ __launch_bounds__(256) void k_conv(const float* __restrict__ x,
    const float* __restrict__ cw, const float* __restrict__ cb,
    float* __restrict__ shift)
{
    size_t idx = (size_t)blockIdx.x * 256 + threadIdx.x;
    int d = (int)(idx % D_);
    size_t n = idx / D_;
    int l = (int)(n % L_);
    float y = cb[d];
    const float* wp = cw + (size_t)d * 4;
#pragma unroll
    for (int i = 0; i < 4; i++) {
        int ll = l - 3 + i;
        if (ll >= 0) y = fmaf(x[idx + (size_t)(i - 3) * D_], wp[i], y);
    }
    shift[idx] = y / (1.f + expf(-y));
}

// ---------------- fp32 NT GEMM: out[n, jo+j] = A[n,:K] . Wm[j,:K] ----------------
// mode 0: plain store. mode 1: out = sigmoid(acc + bias[j]) * xmul[n*ldo + j]
#define BN 64
#define BJ 64
#define BK 16
#define LDP 68

__global__ __launch_bounds__(256) void k_gemm_nt(
    const float* __restrict__ A, const float* __restrict__ Wm,
    float* __restrict__ out, int K, int ldo, int jo,
    int mode, const float* __restrict__ bias, const float* __restrict__ xmul)
{
    __shared__ float As[BK][LDP];
    __shared__ float Ws[BK][LDP];
    int tid = threadIdx.x;
    int n0 = blockIdx.x * BN;
    int j0 = blockIdx.y * BJ;
    int lr = tid >> 2;           // 0..63 tile row
    int lk = (tid & 3) << 2;     // 0,4,8,12 k offset
    int ti = tid >> 4;           // 0..15 output row group
    int tj = tid & 15;           // 0..15 output col group

    float acc[4][4];
#pragma unroll
    for (int i = 0; i < 4; i++)
#pragma unroll
        for (int j = 0; j < 4; j++) acc[i][j] = 0.f;

    for (int k0 = 0; k0 < K; k0 += BK) {
        float4 av = *(const float4*)&A[(size_t)(n0 + lr) * K + k0 + lk];
        float4 wv = *(const float4*)&Wm[(size_t)(j0 + lr) * K + k0 + lk];
        __syncthreads();
        As[lk + 0][lr] = av.x; As[lk + 1][lr] = av.y;
        As[lk + 2][lr] = av.z; As[lk + 3][lr] = av.w;
        Ws[lk + 0][lr] = wv.x; Ws[lk + 1][lr] = wv.y;
        Ws[lk + 2][lr] = wv.z; Ws[lk + 3][lr] = wv.w;
        __syncthreads();
#pragma unroll
        for (int kk = 0; kk < BK; kk++) {
            float4 a = *(const float4*)&As[kk][ti << 2];
            float4 w = *(const float4*)&Ws[kk][tj << 2];
            float aa[4] = {a.x, a.y, a.z, a.w};
            float ww[4] = {w.x, w.y, w.z, w.w};
#pragma unroll
            for (int i = 0; i < 4; i++)
#pragma unroll
                for (int j = 0; j < 4; j++)
                    acc[i][j] = fmaf(aa[i], ww[j], acc[i][j]);
        }
    }

#pragma unroll
    for (int i = 0; i < 4; i++) {
        int n = n0 + (ti << 2) + i;
        int jg = j0 + (tj << 2);
        float vv[4];
#pragma unroll
        for (int j = 0; j < 4; j++) {
            float val = acc[i][j];
            if (mode == 1) {
                val += bias[jg + j];
                val = 1.f / (1.f + expf(-val));
                val *= xmul[(size_t)n * ldo + jo + jg + j];
            }
            vv[j] = val;
        }
        float4 v = {vv[0], vv[1], vv[2], vv[3]};
        *(float4*)&out[(size_t)n * ldo + jo + jg] = v;
    }
}

// ---------------- 5. per-token gate prep ----------------
__global__ __launch_bounds__(64) void k_prep(const float* __restrict__ rkmg,
    const float* __restrict__ mb, float* __restrict__ Rb,
    float* __restrict__ Kb, float* __restrict__ Gb)
{
    int n = blockIdx.x;
    int m = threadIdx.x;
    const float* row = rkmg + (size_t)n * 256;
    float r   = row[m];
    float k   = row[64 + m];
    float mg1 = row[128 + m] + mb[m];
    float mg2 = row[192 + m] + mb[64 + m];
    float sel = (mg1 > 20.f) ? mg1 : log1pf(expf(mg1));
    float tau = 1.f / (1.f + expf(-mg2));
    float it  = expf(tau * logf(sel));        // sel^tau, sel>0 (softplus)
    float g   = -sel * tau;
    float s2  = k * k;
#pragma unroll
    for (int off = 32; off >= 1; off >>= 1) s2 += __shfl_xor(s2, off, 64);
    float kn = k / fmaxf(sqrtf(s2), 1e-12f);
    size_t o = (size_t)n * 64 + m;
    Rb[o] = r;
    Kb[o] = kn * it;
    Gb[o] = expf(g);
}

// ---------------- 6. sequential recurrence ----------------
// 2048 waves (2/SIMD). lane = mg(0..15) x di(0..3).
// Each lane holds S[m, d] for m = mg*4+j (j=0..3), d = d0 + di.
// Register prefetch pipeline of depth 8 hides L2/HBM latency.
struct TS { float4 r, k, g; float uv, sv; };

__device__ __forceinline__ void ld_ts(TS& s,
    const float* __restrict__ Rp, const float* __restrict__ Kp,
    const float* __restrict__ Gp, const float* __restrict__ up,
    const float* __restrict__ sp, int t)
{
    s.r = *(const float4*)(Rp + (size_t)t * 64);
    s.k = *(const float4*)(Kp + (size_t)t * 64);
    s.g = *(const float4*)(Gp + (size_t)t * 64);
    s.uv = up[(size_t)t * D_];
    s.sv = sp[(size_t)t * D_];
}

__device__ __forceinline__ void step_ts(const TS& c, float S[4], float rwv,
    float* __restrict__ op, int t, int lane)
{
    float p;
    S[0] = fmaf(c.g.x, S[0], c.k.x * c.uv); p = c.r.x * S[0];
    S[1] = fmaf(c.g.y, S[1], c.k.y * c.uv); p = fmaf(c.r.y, S[1], p);
    S[2] = fmaf(c.g.z, S[2], c.k.z * c.uv); p = fmaf(c.r.z, S[2], p);
    S[3] = fmaf(c.g.w, S[3], c.k.w * c.uv); p = fmaf(c.r.w, S[3], p);
    p += __shfl_xor(p, 4, 64);
    p += __shfl_xor(p, 8, 64);
    p += __shfl_xor(p, 16, 64);
    p += __shfl_xor(p, 32, 64);
    if (lane < 4)
        op[(size_t)t * D_] = SCALE_ * p + c.sv * rwv;
}

__global__ __launch_bounds__(64) void k_rec(const float* __restrict__ Rb,
    const float* __restrict__ Kb, const float* __restrict__ Gb,
    const float* __restrict__ u, const float* __restrict__ shift,
    const float* __restrict__ rw, float* __restrict__ out)
{
    int wid = blockIdx.x;            // 0..2047
    int b = wid >> 9;                // 512 d-tiles per batch
    int d0 = (wid & 511) << 2;       // tile of 4 d-columns
    int lane = threadIdx.x;
    int mg = lane >> 2;              // 0..15 m-group (4 m's each)
    int di = lane & 3;               // 0..3 d-column within tile
    int d = d0 + di;

    float S[4] = {0.f, 0.f, 0.f, 0.f};
    float rwv = rw[d];

    size_t base = (size_t)b * L_ * D_ + d;
    const float* up = u + base;
    const float* sp = shift + base;
    float* op = out + base;
    size_t pbase = (size_t)b * L_ * 64 + mg * 4;
    const float* Rp = Rb + pbase;
    const float* Kp = Kb + pbase;
    const float* Gp = Gb + pbase;

    TS buf[8];
#pragma unroll
    for (int p = 0; p < 8; p++) ld_ts(buf[p], Rp, Kp, Gp, up, sp, p);

    int t = 0;
    for (; t < L_ - 8; t += 8) {
#pragma unroll
        for (int j = 0; j < 8; j++) {
            TS nx;
            ld_ts(nx, Rp, Kp, Gp, up, sp, t + 8 + j);
            step_ts(buf[j], S, rwv, op, t + j, lane);
            buf[j] = nx;
        }
    }
#pragma unroll
    for (int j = 0; j < 8; j++) step_ts(buf[j], S, rwv, op, t + j, lane);
}

// ---------------- launcher ----------------
extern "C" void kernel_launch(void* const* d_in, const int* in_sizes, int n_in,
                              void* d_out, int out_size, void* d_ws, size_t ws_size,
                              hipStream_t stream)
{
    const float* x   = (const float*)d_in[0];
    const float* cw  = (const float*)d_in[1];
    const float* cb  = (const float*)d_in[2];
    const float* ipw = (const float*)d_in[3];  // (128, 2048)
    const float* w0  = (const float*)d_in[4];  // (128, 2048)
    const float* w1  = (const float*)d_in[5];  // (2048, 128)
    const float* b1  = (const float*)d_in[6];
    const float* mw  = (const float*)d_in[7];  // (128, 2048)
    const float* mb  = (const float*)d_in[8];
    const float* rw  = (const float*)d_in[9];
    float* out = (float*)d_out;

    float* ws    = (float*)d_ws;
    float* shift = ws;                              // 16,777,216 f
    float* u     = shift + (size_t)NTOK * D_;       // 16,777,216 f
    float* rkmg  = u + (size_t)NTOK * D_;           //  2,097,152 f
    float* t1    = rkmg + (size_t)NTOK * 256;       //  1,048,576 f
    float* Rb    = t1 + (size_t)NTOK * R_;          //    524,288 f
    float* Kb    = Rb + (size_t)NTOK * 64;
    float* Gb    = Kb + (size_t)NTOK * 64;

    // 1. shift = silu(causal_conv(x))
    k_conv<<<(NTOK * (size_t)D_) / 256, 256, 0, stream>>>(x, cw, cb, shift);

    // 2. rkmg[:, :128] = shift @ in_proj_w^T ; rkmg[:, 128:] = shift @ mem_gate_w^T
    dim3 g2(NTOK / BN, 128 / BJ);
    k_gemm_nt<<<g2, 256, 0, stream>>>(shift, ipw, rkmg, D_, 256, 0,   0, nullptr, nullptr);
    k_gemm_nt<<<g2, 256, 0, stream>>>(shift, mw,  rkmg, D_, 256, 128, 0, nullptr, nullptr);

    // 3. t1 = x @ ch_gate_w0^T
    k_gemm_nt<<<dim3(NTOK / BN, R_ / BJ), 256, 0, stream>>>(x, w0, t1, D_, R_, 0, 0, nullptr, nullptr);

    // 4. u = sigmoid(t1 @ ch_gate_w1^T + b1) * x
    k_gemm_nt<<<dim3(NTOK / BN, D_ / BJ), 256, 0, stream>>>(t1, w1, u, R_, D_, 0, 1, b1, x);

    // 5. gate prep: r, k_hat*it_gate, exp(g)
    k_prep<<<NTOK, 64, 0, stream>>>(rkmg, mb, Rb, Kb, Gb);

    // 6. recurrence + residual epilogue (2048 waves, depth-8 prefetch)
    k_rec<<<2048, 64, 0, stream>>>(Rb, Kb, Gb, u, shift, rw, out);
}

// Round 3
// 988.274 us; speedup vs baseline: 1.4455x; 1.1641x over previous
//
#include <hip/hip_runtime.h>
#include <hip/hip_bf16.h>
#include <math.h>

#define B_ 4
#define L_ 2048
#define D_ 2048
#define M_ 64
#define R_ 128
#define NTOK (B_*L_)
#define SCALE_ 0.125f

typedef __attribute__((ext_vector_type(8))) short short8;
typedef __attribute__((ext_vector_type(4))) float f32x4;

// ---------------- 1. causal depthwise conv (W=4) + silu ----------------
__global__ __launch_bounds__(256) void k_conv(const float* __restrict__ x,
    const float* __restrict__ cw, const float* __restrict__ cb,
    float* __restrict__ shift)
{
    size_t idx = (size_t)blockIdx.x * 256 + threadIdx.x;
    int d = (int)(idx % D_);
    size_t n = idx / D_;
    int l = (int)(n % L_);
    float y = cb[d];
    const float* wp = cw + (size_t)d * 4;
#pragma unroll
    for (int i = 0; i < 4; i++) {
        int ll = l - 3 + i;
        if (ll >= 0) y = fmaf(x[idx + (size_t)(i - 3) * D_], wp[i], y);
    }
    shift[idx] = y / (1.f + expf(-y));
}

// ---------------- weight cast fp32 -> bf16 (4 matrices of 128*2048) ----------------
__device__ __forceinline__ unsigned pkbf(float a, float b) {
    union { __hip_bfloat162 h; unsigned u; } cv;
    cv.h = __float22bfloat162_rn(make_float2(a, b));
    return cv.u;
}

__global__ __launch_bounds__(256) void k_castw(
    const float* __restrict__ s0, const float* __restrict__ s1,
    const float* __restrict__ s2, const float* __restrict__ s3,
    unsigned short* __restrict__ d0, unsigned short* __restrict__ d1,
    unsigned short* __restrict__ d2, unsigned short* __restrict__ d3)
{
    int which = blockIdx.x >> 8;                       // 256 blocks per matrix
    int idx = ((blockIdx.x & 255) * 256 + threadIdx.x) * 4;
    const float* s = which == 0 ? s0 : which == 1 ? s1 : which == 2 ? s2 : s3;
    unsigned short* d = which == 0 ? d0 : which == 1 ? d1 : which == 2 ? d2 : d3;
    float4 v = *(const float4*)(s + idx);
    uint2 o;
    o.x = pkbf(v.x, v.y);
    o.y = pkbf(v.z, v.w);
    *(uint2*)(d + idx) = o;
}

// ---------------- bf16 MFMA NT GEMM: out[n, jo+j] = A[n,:K] . B[j,:K] ----------------
// A fp32 in HBM (converted to bf16 during LDS staging), B pre-cast bf16 [J][K].
// 128x128 tile, 256 threads = 4 waves, each wave 64x64 = 4x4 MFMA tiles (16x16x32).
// mode 0: store fp32. mode 1: out = sigmoid(acc + bias[j]) * xmul[n*ldo + j]
__global__ __launch_bounds__(256) void k_mfma_nt(
    const float* __restrict__ A, const unsigned short* __restrict__ Bb,
    float* __restrict__ out, int K, int ldo, int jo,
    int mode, const float* __restrict__ bias, const float* __restrict__ xmul)
{
    __shared__ unsigned short As[128 * 32];
    __shared__ unsigned short Bs[128 * 32];
    int tid = threadIdx.x;
    int n0 = blockIdx.x * 128;
    int jblk = blockIdx.y * 128;
    int wave = tid >> 6, lane = tid & 63;
    int quad = lane >> 4, lcol = lane & 15;
    int wrow = (wave >> 1) * 64, wcol = (wave & 1) * 64;

    f32x4 acc[4][4];
#pragma unroll
    for (int i = 0; i < 4; i++)
#pragma unroll
        for (int j = 0; j < 4; j++) acc[i][j] = {0.f, 0.f, 0.f, 0.f};

    for (int k0 = 0; k0 < K; k0 += 32) {
        // global loads first (overlap with previous compute draining)
        float4 a0[2][2];
        uint4 bv[2];
#pragma unroll
        for (int p = 0; p < 2; p++) {
            int idx = p * 256 + tid;
            int row = idx >> 2, sub = idx & 3;       // row 0..127, 8-elem segment
            const float* ap = A + (size_t)(n0 + row) * K + k0 + sub * 8;
            a0[p][0] = *(const float4*)ap;
            a0[p][1] = *(const float4*)(ap + 4);
            bv[p] = *(const uint4*)(Bb + (size_t)(jblk + row) * K + k0 + sub * 8);
        }
        __syncthreads();                              // prior MFMA reads of LDS done
#pragma unroll
        for (int p = 0; p < 2; p++) {
            int idx = p * 256 + tid;
            int row = idx >> 2, sub = idx & 3;
            uint4 w;
            w.x = pkbf(a0[p][0].x, a0[p][0].y);
            w.y = pkbf(a0[p][0].z, a0[p][0].w);
            w.z = pkbf(a0[p][1].x, a0[p][1].y);
            w.w = pkbf(a0[p][1].z, a0[p][1].w);
            *(uint4*)&As[row * 32 + sub * 8] = w;
            *(uint4*)&Bs[row * 32 + sub * 8] = bv[p];
        }
        __syncthreads();
        short8 af[4], bfr[4];
#pragma unroll
        for (int i = 0; i < 4; i++)
            af[i] = *(short8*)&As[(wrow + i * 16 + lcol) * 32 + quad * 8];
#pragma unroll
        for (int j = 0; j < 4; j++)
            bfr[j] = *(short8*)&Bs[(wcol + j * 16 + lcol) * 32 + quad * 8];
#pragma unroll
        for (int i = 0; i < 4; i++)
#pragma unroll
            for (int j = 0; j < 4; j++)
                acc[i][j] = __builtin_amdgcn_mfma_f32_16x16x32_bf16(
                    af[i], bfr[j], acc[i][j], 0, 0, 0);
    }

    // epilogue: D[row=(lane>>4)*4+reg][col=lane&15] per 16x16 tile (m89-verified)
#pragma unroll
    for (int i = 0; i < 4; i++) {
#pragma unroll
        for (int j = 0; j < 4; j++) {
#pragma unroll
            for (int q = 0; q < 4; q++) {
                int row = wrow + i * 16 + quad * 4 + q;
                int col = wcol + j * 16 + lcol;
                int n = n0 + row;
                int jc = jblk + col;
                float val = acc[i][j][q];
                if (mode == 1) {
                    val += bias[jc];
                    val = 1.f / (1.f + expf(-val));
                    val *= xmul[(size_t)n * ldo + jo + jc];
                }
                out[(size_t)n * ldo + jo + jc] = val;
            }
        }
    }
}

// ---------------- 5. per-token gate prep ----------------
__global__ __launch_bounds__(64) void k_prep(const float* __restrict__ rkmg,
    const float* __restrict__ mb, float* __restrict__ Rb,
    float* __restrict__ Kb, float* __restrict__ Gb)
{
    int n = blockIdx.x;
    int m = threadIdx.x;
    const float* row = rkmg + (size_t)n * 256;
    float r   = row[m];
    float k   = row[64 + m];
    float mg1 = row[128 + m] + mb[m];
    float mg2 = row[192 + m] + mb[64 + m];
    float sel = (mg1 > 20.f) ? mg1 : log1pf(expf(mg1));
    float tau = 1.f / (1.f + expf(-mg2));
    float it  = expf(tau * logf(sel));        // sel^tau, sel>0 (softplus)
    float g   = -sel * tau;
    float s2  = k * k;
#pragma unroll
    for (int off = 32; off >= 1; off >>= 1) s2 += __shfl_xor(s2, off, 64);
    float kn = k / fmaxf(sqrtf(s2), 1e-12f);
    size_t o = (size_t)n * 64 + m;
    Rb[o] = r;
    Kb[o] = kn * it;
    Gb[o] = expf(g);
}

// ---------------- 6. sequential recurrence (unchanged from R2) ----------------
struct TS { float4 r, k, g; float uv, sv; };

__device__ __forceinline__ void ld_ts(TS& s,
    const float* __restrict__ Rp, const float* __restrict__ Kp,
    const float* __restrict__ Gp, const float* __restrict__ up,
    const float* __restrict__ sp, int t)
{
    s.r = *(const float4*)(Rp + (size_t)t * 64);
    s.k = *(const float4*)(Kp + (size_t)t * 64);
    s.g = *(const float4*)(Gp + (size_t)t * 64);
    s.uv = up[(size_t)t * D_];
    s.sv = sp[(size_t)t * D_];
}

__device__ __forceinline__ void step_ts(const TS& c, float S[4], float rwv,
    float* __restrict__ op, int t, int lane)
{
    float p;
    S[0] = fmaf(c.g.x, S[0], c.k.x * c.uv); p = c.r.x * S[0];
    S[1] = fmaf(c.g.y, S[1], c.k.y * c.uv); p = fmaf(c.r.y, S[1], p);
    S[2] = fmaf(c.g.z, S[2], c.k.z * c.uv); p = fmaf(c.r.z, S[2], p);
    S[3] = fmaf(c.g.w, S[3], c.k.w * c.uv); p = fmaf(c.r.w, S[3], p);
    p += __shfl_xor(p, 4, 64);
    p += __shfl_xor(p, 8, 64);
    p += __shfl_xor(p, 16, 64);
    p += __shfl_xor(p, 32, 64);
    if (lane < 4)
        op[(size_t)t * D_] = SCALE_ * p + c.sv * rwv;
}

__global__ __launch_bounds__(64) void k_rec(const float* __restrict__ Rb,
    const float* __restrict__ Kb, const float* __restrict__ Gb,
    const float* __restrict__ u, const float* __restrict__ shift,
    const float* __restrict__ rw, float* __restrict__ out)
{
    int wid = blockIdx.x;            // 0..2047
    int b = wid >> 9;
    int d0 = (wid & 511) << 2;
    int lane = threadIdx.x;
    int mg = lane >> 2;
    int di = lane & 3;
    int d = d0 + di;

    float S[4] = {0.f, 0.f, 0.f, 0.f};
    float rwv = rw[d];

    size_t base = (size_t)b * L_ * D_ + d;
    const float* up = u + base;
    const float* sp = shift + base;
    float* op = out + base;
    size_t pbase = (size_t)b * L_ * 64 + mg * 4;
    const float* Rp = Rb + pbase;
    const float* Kp = Kb + pbase;
    const float* Gp = Gb + pbase;

    TS buf[8];
#pragma unroll
    for (int p = 0; p < 8; p++) ld_ts(buf[p], Rp, Kp, Gp, up, sp, p);

    int t = 0;
    for (; t < L_ - 8; t += 8) {
#pragma unroll
        for (int j = 0; j < 8; j++) {
            TS nx;
            ld_ts(nx, Rp, Kp, Gp, up, sp, t + 8 + j);
            step_ts(buf[j], S, rwv, op, t + j, lane);
            buf[j] = nx;
        }
    }
#pragma unroll
    for (int j = 0; j < 8; j++) step_ts(buf[j], S, rwv, op, t + j, lane);
}

// ---------------- launcher ----------------
extern "C" void kernel_launch(void* const* d_in, const int* in_sizes, int n_in,
                              void* d_out, int out_size, void* d_ws, size_t ws_size,
                              hipStream_t stream)
{
    const float* x   = (const float*)d_in[0];
    const float* cw  = (const float*)d_in[1];
    const float* cb  = (const float*)d_in[2];
    const float* ipw = (const float*)d_in[3];  // (128, 2048)
    const float* w0  = (const float*)d_in[4];  // (128, 2048)
    const float* w1  = (const float*)d_in[5];  // (2048, 128)
    const float* b1  = (const float*)d_in[6];
    const float* mw  = (const float*)d_in[7];  // (128, 2048)
    const float* mb  = (const float*)d_in[8];
    const float* rw  = (const float*)d_in[9];
    float* out = (float*)d_out;

    float* ws    = (float*)d_ws;
    float* shift = ws;                              // 16,777,216 f
    float* u     = shift + (size_t)NTOK * D_;       // 16,777,216 f
    float* rkmg  = u + (size_t)NTOK * D_;           //  2,097,152 f
    float* t1    = rkmg + (size_t)NTOK * 256;       //  1,048,576 f
    float* Rb    = t1 + (size_t)NTOK * R_;          //    524,288 f
    float* Kb    = Rb + (size_t)NTOK * 64;
    float* Gb    = Kb + (size_t)NTOK * 64;
    unsigned short* Wcatb = (unsigned short*)(Gb + (size_t)NTOK * 64); // 256*2048 us
    unsigned short* w0b   = Wcatb + 256 * 2048;     // 128*2048 us
    unsigned short* w1b   = w0b + 128 * 2048;       // 2048*128 us

    // 1. shift = silu(causal_conv(x))
    k_conv<<<(NTOK * (size_t)D_) / 256, 256, 0, stream>>>(x, cw, cb, shift);

    // 1b. weight casts: Wcatb = bf16([ipw; mw]), w0b, w1b
    k_castw<<<1024, 256, 0, stream>>>(ipw, mw, w0, w1,
                                      Wcatb, Wcatb + 128 * 2048, w0b, w1b);

    // 2. rkmg = shift @ [ipw; mw]^T   (N=8192, J=256, K=2048)
    k_mfma_nt<<<dim3(64, 2), 256, 0, stream>>>(shift, Wcatb, rkmg, D_, 256, 0,
                                               0, nullptr, nullptr);

    // 3. t1 = x @ ch_gate_w0^T        (N=8192, J=128, K=2048)
    k_mfma_nt<<<dim3(64, 1), 256, 0, stream>>>(x, w0b, t1, D_, R_, 0,
                                               0, nullptr, nullptr);

    // 4. u = sigmoid(t1 @ ch_gate_w1^T + b1) * x   (N=8192, J=2048, K=128)
    k_mfma_nt<<<dim3(64, 16), 256, 0, stream>>>(t1, w1b, u, R_, D_, 0,
                                                1, b1, x);

    // 5. gate prep: r, k_hat*it_gate, exp(g)
    k_prep<<<NTOK, 64, 0, stream>>>(rkmg, mb, Rb, Kb, Gb);

    // 6. recurrence + residual epilogue (2048 waves, depth-8 prefetch)
    k_rec<<<2048, 64, 0, stream>>>(Rb, Kb, Gb, u, shift, rw, out);
}

// Round 4
// 782.314 us; speedup vs baseline: 1.8261x; 1.2633x over previous
//
#include <hip/hip_runtime.h>
#include <hip/hip_bf16.h>
#include <math.h>

#define B_ 4
#define L_ 2048
#define D_ 2048
#define M_ 64
#define R_ 128
#define NTOK (B_*L_)
#define SCALE_ 0.125f
#define C_ 16
#define DS 16

typedef __attribute__((ext_vector_type(8))) short short8;
typedef __attribute__((ext_vector_type(4))) float f32x4;

// ---------------- 1. causal depthwise conv (W=4) + silu ----------------
__global__ __launch_bounds__(256) void k_conv(const float* __restrict__ x,
    const float* __restrict__ cw, const float* __restrict__ cb,
    float* __restrict__ shift)
{
    size_t idx = (size_t)blockIdx.x * 256 + threadIdx.x;
    int d = (int)(idx % D_);
    size_t n = idx / D_;
    int l = (int)(n % L_);
    float y = cb[d];
    const float* wp = cw + (size_t)d * 4;
#pragma unroll
    for (int i = 0; i < 4; i++) {
        int ll = l - 3 + i;
        if (ll >= 0) y = fmaf(x[idx + (size_t)(i - 3) * D_], wp[i], y);
    }
    shift[idx] = y / (1.f + expf(-y));
}

// ---------------- weight cast fp32 -> bf16 ----------------
__device__ __forceinline__ unsigned pkbf(float a, float b) {
    union { __hip_bfloat162 h; unsigned u; } cv;
    cv.h = __float22bfloat162_rn(make_float2(a, b));
    return cv.u;
}

__global__ __launch_bounds__(256) void k_castw(
    const float* __restrict__ s0, const float* __restrict__ s1,
    const float* __restrict__ s2, const float* __restrict__ s3,
    unsigned short* __restrict__ d0, unsigned short* __restrict__ d1,
    unsigned short* __restrict__ d2, unsigned short* __restrict__ d3)
{
    int which = blockIdx.x >> 8;
    int idx = ((blockIdx.x & 255) * 256 + threadIdx.x) * 4;
    const float* s = which == 0 ? s0 : which == 1 ? s1 : which == 2 ? s2 : s3;
    unsigned short* d = which == 0 ? d0 : which == 1 ? d1 : which == 2 ? d2 : d3;
    float4 v = *(const float4*)(s + idx);
    uint2 o;
    o.x = pkbf(v.x, v.y);
    o.y = pkbf(v.z, v.w);
    *(uint2*)(d + idx) = o;
}

// ---------------- bf16 MFMA NT GEMM (unchanged from R3) ----------------
__global__ __launch_bounds__(256) void k_mfma_nt(
    const float* __restrict__ A, const unsigned short* __restrict__ Bb,
    float* __restrict__ out, int K, int ldo, int jo,
    int mode, const float* __restrict__ bias, const float* __restrict__ xmul)
{
    __shared__ unsigned short As[128 * 32];
    __shared__ unsigned short Bs[128 * 32];
    int tid = threadIdx.x;
    int n0 = blockIdx.x * 128;
    int jblk = blockIdx.y * 128;
    int wave = tid >> 6, lane = tid & 63;
    int quad = lane >> 4, lcol = lane & 15;
    int wrow = (wave >> 1) * 64, wcol = (wave & 1) * 64;

    f32x4 acc[4][4];
#pragma unroll
    for (int i = 0; i < 4; i++)
#pragma unroll
        for (int j = 0; j < 4; j++) acc[i][j] = {0.f, 0.f, 0.f, 0.f};

    for (int k0 = 0; k0 < K; k0 += 32) {
        float4 a0[2][2];
        uint4 bv[2];
#pragma unroll
        for (int p = 0; p < 2; p++) {
            int idx = p * 256 + tid;
            int row = idx >> 2, sub = idx & 3;
            const float* ap = A + (size_t)(n0 + row) * K + k0 + sub * 8;
            a0[p][0] = *(const float4*)ap;
            a0[p][1] = *(const float4*)(ap + 4);
            bv[p] = *(const uint4*)(Bb + (size_t)(jblk + row) * K + k0 + sub * 8);
        }
        __syncthreads();
#pragma unroll
        for (int p = 0; p < 2; p++) {
            int idx = p * 256 + tid;
            int row = idx >> 2, sub = idx & 3;
            uint4 w;
            w.x = pkbf(a0[p][0].x, a0[p][0].y);
            w.y = pkbf(a0[p][0].z, a0[p][0].w);
            w.z = pkbf(a0[p][1].x, a0[p][1].y);
            w.w = pkbf(a0[p][1].z, a0[p][1].w);
            *(uint4*)&As[row * 32 + sub * 8] = w;
            *(uint4*)&Bs[row * 32 + sub * 8] = bv[p];
        }
        __syncthreads();
        short8 af[4], bfr[4];
#pragma unroll
        for (int i = 0; i < 4; i++)
            af[i] = *(short8*)&As[(wrow + i * 16 + lcol) * 32 + quad * 8];
#pragma unroll
        for (int j = 0; j < 4; j++)
            bfr[j] = *(short8*)&Bs[(wcol + j * 16 + lcol) * 32 + quad * 8];
#pragma unroll
        for (int i = 0; i < 4; i++)
#pragma unroll
            for (int j = 0; j < 4; j++)
                acc[i][j] = __builtin_amdgcn_mfma_f32_16x16x32_bf16(
                    af[i], bfr[j], acc[i][j], 0, 0, 0);
    }

#pragma unroll
    for (int i = 0; i < 4; i++) {
#pragma unroll
        for (int j = 0; j < 4; j++) {
#pragma unroll
            for (int q = 0; q < 4; q++) {
                int row = wrow + i * 16 + quad * 4 + q;
                int col = wcol + j * 16 + lcol;
                int n = n0 + row;
                int jc = jblk + col;
                float val = acc[i][j][q];
                if (mode == 1) {
                    val += bias[jc];
                    val = 1.f / (1.f + expf(-val));
                    val *= xmul[(size_t)n * ldo + jo + jc];
                }
                out[(size_t)n * ldo + jo + jc] = val;
            }
        }
    }
}

// ---------------- 5. per-token gate prep (Gb now stores RAW g) ----------------
__global__ __launch_bounds__(64) void k_prep(const float* __restrict__ rkmg,
    const float* __restrict__ mb, float* __restrict__ Rb,
    float* __restrict__ Kb, float* __restrict__ Gb)
{
    int n = blockIdx.x;
    int m = threadIdx.x;
    const float* row = rkmg + (size_t)n * 256;
    float r   = row[m];
    float k   = row[64 + m];
    float mg1 = row[128 + m] + mb[m];
    float mg2 = row[192 + m] + mb[64 + m];
    float sel = (mg1 > 20.f) ? mg1 : log1pf(expf(mg1));
    float tau = 1.f / (1.f + expf(-mg2));
    float it  = expf(tau * logf(sel));
    float g   = -sel * tau;
    float s2  = k * k;
#pragma unroll
    for (int off = 32; off >= 1; off >>= 1) s2 += __shfl_xor(s2, off, 64);
    float kn = k / fmaxf(sqrtf(s2), 1e-12f);
    size_t o = (size_t)n * 64 + m;
    Rb[o] = r;
    Kb[o] = kn * it;
    Gb[o] = g;                  // raw log-decay for chunked scan
}

// ---------------- 6. chunked recurrence (C=16, d-slice=16) ----------------
// block = (batch, 16-d slice); 512 blocks x 256 threads.
// S[m][d] kept in LDS as Ssh[dd*68 + m] (fp32).
__global__ __launch_bounds__(256) void k_chunk(
    const float* __restrict__ Rb, const float* __restrict__ Kb,
    const float* __restrict__ Gb, const float* __restrict__ u,
    const float* __restrict__ shift, const float* __restrict__ rw,
    float* __restrict__ out)
{
    __shared__ __align__(16) float rS[16 * 64];
    __shared__ __align__(16) float kS[16 * 64];
    __shared__ __align__(16) float gS[16 * 64];
    __shared__ __align__(16) float us[16 * 16];
    __shared__ __align__(16) float rt[16 * 68];
    __shared__ __align__(16) float kd[16 * 68];
    __shared__ __align__(16) float kc[16 * 68];
    __shared__ __align__(16) float Ssh[16 * 68];
    __shared__ __align__(16) float Psh[16 * 17];
    __shared__ __align__(16) float seg[4 * 64];
    __shared__ __align__(16) float aC[64];

    int tid = threadIdx.x;
    int bid = blockIdx.x;
    int b = bid & 3;            // batch interleaved over XCDs for R/K/G L2 locality
    int slice = bid >> 2;
    int d0 = slice * DS;

    int i4 = tid >> 4;          // 0..15 token-in-chunk (stage / P-row / o-row / m-group)
    int dd = tid & 15;          // 0..15 d-in-slice
    int mm = tid & 63;          // 0..63 m for decay transform
    int sg = tid >> 6;          // 0..3 segment of 4 tokens

    for (int i = tid; i < 16 * 68; i += 256) Ssh[i] = 0.f;

    float rwv = rw[d0 + dd];

    size_t tokbase = (size_t)b * L_ * 64;
    size_t ubase = (size_t)b * L_ * D_ + d0;

    // prefetch chunk 0
    float4 rv, kv, gv;
    float uv, shv;
    {
        size_t g0 = tokbase + (size_t)tid * 4;
        rv = *(const float4*)(Rb + g0);
        kv = *(const float4*)(Kb + g0);
        gv = *(const float4*)(Gb + g0);
        uv  = u[ubase + (size_t)i4 * D_ + dd];
        shv = shift[ubase + (size_t)i4 * D_ + dd];
    }

    for (int c = 0; c < L_ / C_; c++) {
        int t0 = c * C_;
        // ---- stage prefetched regs -> LDS ----
        *(float4*)&rS[tid * 4] = rv;
        *(float4*)&kS[tid * 4] = kv;
        *(float4*)&gS[tid * 4] = gv;
        us[i4 * 16 + dd] = uv;
        __syncthreads();

        // ---- decay transform: Lambda cumsum, rt/kd/kc/aC ----
        {
            float g0v = gS[(sg * 4 + 0) * 64 + mm];
            float g1v = gS[(sg * 4 + 1) * 64 + mm];
            float g2v = gS[(sg * 4 + 2) * 64 + mm];
            float g3v = gS[(sg * 4 + 3) * 64 + mm];
            float c0 = g0v, c1 = c0 + g1v, c2 = c1 + g2v, c3 = c2 + g3v;
            seg[sg * 64 + mm] = c3;
            __syncthreads();
            float off = 0.f, tot = 0.f;
#pragma unroll
            for (int s = 0; s < 4; s++) {
                float v = seg[s * 64 + mm];
                if (s < sg) off += v;
                tot += v;
            }
            float l0 = off + c0, l1 = off + c1, l2 = off + c2, l3 = off + c3;
            int i0 = sg * 4;
            float r0 = rS[(i0 + 0) * 64 + mm], k0 = kS[(i0 + 0) * 64 + mm];
            float r1 = rS[(i0 + 1) * 64 + mm], k1 = kS[(i0 + 1) * 64 + mm];
            float r2 = rS[(i0 + 2) * 64 + mm], k2 = kS[(i0 + 2) * 64 + mm];
            float r3 = rS[(i0 + 3) * 64 + mm], k3 = kS[(i0 + 3) * 64 + mm];
            rt[(i0 + 0) * 68 + mm] = r0 * expf(l0);
            rt[(i0 + 1) * 68 + mm] = r1 * expf(l1);
            rt[(i0 + 2) * 68 + mm] = r2 * expf(l2);
            rt[(i0 + 3) * 68 + mm] = r3 * expf(l3);
            kd[(i0 + 0) * 68 + mm] = k0 * expf(-l0);
            kd[(i0 + 1) * 68 + mm] = k1 * expf(-l1);
            kd[(i0 + 2) * 68 + mm] = k2 * expf(-l2);
            kd[(i0 + 3) * 68 + mm] = k3 * expf(-l3);
            kc[(i0 + 0) * 68 + mm] = k0 * expf(tot - l0);
            kc[(i0 + 1) * 68 + mm] = k1 * expf(tot - l1);
            kc[(i0 + 2) * 68 + mm] = k2 * expf(tot - l2);
            kc[(i0 + 3) * 68 + mm] = k3 * expf(tot - l3);
            if (sg == 0) aC[mm] = expf(tot);
        }
        __syncthreads();

        // prefetch next chunk (hidden under P/o/S compute)
        if (c + 1 < L_ / C_) {
            size_t g0 = tokbase + (size_t)(t0 + C_) * 64 + (size_t)tid * 4;
            rv = *(const float4*)(Rb + g0);
            kv = *(const float4*)(Kb + g0);
            gv = *(const float4*)(Gb + g0);
            uv  = u[ubase + (size_t)(t0 + C_ + i4) * D_ + dd];
            shv = shift[ubase + (size_t)(t0 + C_ + i4) * D_ + dd];
        }

        // ---- P[t][s] = sum_m rt[t][m] * kd[s][m], causal ----
        {
            int t = i4, s = dd;
            float p = 0.f;
            if (s <= t) {
#pragma unroll
                for (int mt = 0; mt < 16; mt++) {
                    float4 a = *(const float4*)&rt[t * 68 + mt * 4];
                    float4 q = *(const float4*)&kd[s * 68 + mt * 4];
                    p = fmaf(a.x, q.x, p); p = fmaf(a.y, q.y, p);
                    p = fmaf(a.z, q.z, p); p = fmaf(a.w, q.w, p);
                }
            }
            Psh[t * 17 + s] = p;
        }
        __syncthreads();

        // ---- o[i][dd] = SCALE*(P@U + rt@S) + shift*rw ----
        {
            float acc = 0.f;
#pragma unroll
            for (int s = 0; s < 16; s++)
                acc = fmaf(Psh[i4 * 17 + s], us[s * 16 + dd], acc);
#pragma unroll
            for (int mt = 0; mt < 16; mt++) {
                float4 sv = *(const float4*)&Ssh[dd * 68 + mt * 4];
                float4 a  = *(const float4*)&rt[i4 * 68 + mt * 4];
                acc = fmaf(a.x, sv.x, acc); acc = fmaf(a.y, sv.y, acc);
                acc = fmaf(a.z, sv.z, acc); acc = fmaf(a.w, sv.w, acc);
            }
            size_t oa = ubase + (size_t)(t0 + i4) * D_ + dd;
            float shcur = (c == 0) ? shv : 0.f;  // careful: shv holds NEXT chunk after prefetch
            (void)shcur;
            out[oa] = SCALE_ * acc + shift[oa] * rwv;
        }
        __syncthreads();

        // ---- S update: S = aC*S + kc^T @ U ----
        {
            int m0 = i4 * 4;
            float4 sv = *(const float4*)&Ssh[dd * 68 + m0];
            float4 a4 = *(const float4*)&aC[m0];
            sv.x *= a4.x; sv.y *= a4.y; sv.z *= a4.z; sv.w *= a4.w;
#pragma unroll
            for (int s = 0; s < 16; s++) {
                float uu = us[s * 16 + dd];
                float4 k4 = *(const float4*)&kc[s * 68 + m0];
                sv.x = fmaf(k4.x, uu, sv.x); sv.y = fmaf(k4.y, uu, sv.y);
                sv.z = fmaf(k4.z, uu, sv.z); sv.w = fmaf(k4.w, uu, sv.w);
            }
            *(float4*)&Ssh[dd * 68 + m0] = sv;
        }
        __syncthreads();
    }
}

// ---------------- launcher ----------------
extern "C" void kernel_launch(void* const* d_in, const int* in_sizes, int n_in,
                              void* d_out, int out_size, void* d_ws, size_t ws_size,
                              hipStream_t stream)
{
    const float* x   = (const float*)d_in[0];
    const float* cw  = (const float*)d_in[1];
    const float* cb  = (const float*)d_in[2];
    const float* ipw = (const float*)d_in[3];
    const float* w0  = (const float*)d_in[4];
    const float* w1  = (const float*)d_in[5];
    const float* b1  = (const float*)d_in[6];
    const float* mw  = (const float*)d_in[7];
    const float* mb  = (const float*)d_in[8];
    const float* rw  = (const float*)d_in[9];
    float* out = (float*)d_out;

    float* ws    = (float*)d_ws;
    float* shift = ws;
    float* u     = shift + (size_t)NTOK * D_;
    float* rkmg  = u + (size_t)NTOK * D_;
    float* t1    = rkmg + (size_t)NTOK * 256;
    float* Rb    = t1 + (size_t)NTOK * R_;
    float* Kb    = Rb + (size_t)NTOK * 64;
    float* Gb    = Kb + (size_t)NTOK * 64;
    unsigned short* Wcatb = (unsigned short*)(Gb + (size_t)NTOK * 64);
    unsigned short* w0b   = Wcatb + 256 * 2048;
    unsigned short* w1b   = w0b + 128 * 2048;

    k_conv<<<(NTOK * (size_t)D_) / 256, 256, 0, stream>>>(x, cw, cb, shift);

    k_castw<<<1024, 256, 0, stream>>>(ipw, mw, w0, w1,
                                      Wcatb, Wcatb + 128 * 2048, w0b, w1b);

    k_mfma_nt<<<dim3(64, 2), 256, 0, stream>>>(shift, Wcatb, rkmg, D_, 256, 0,
                                               0, nullptr, nullptr);
    k_mfma_nt<<<dim3(64, 1), 256, 0, stream>>>(x, w0b, t1, D_, R_, 0,
                                               0, nullptr, nullptr);
    k_mfma_nt<<<dim3(64, 16), 256, 0, stream>>>(t1, w1b, u, R_, D_, 0,
                                                1, b1, x);

    k_prep<<<NTOK, 64, 0, stream>>>(rkmg, mb, Rb, Kb, Gb);

    k_chunk<<<512, 256, 0, stream>>>(Rb, Kb, Gb, u, shift, rw, out);
}

// Round 5
// 663.020 us; speedup vs baseline: 2.1547x; 1.1799x over previous
//
#include <hip/hip_runtime.h>
#include <hip/hip_bf16.h>
#include <math.h>

#define B_ 4
#define L_ 2048
#define D_ 2048
#define M_ 64
#define R_ 128
#define NTOK (B_*L_)
#define SCALE_ 0.125f
#define C_ 16
#define NCH (L_/C_)

typedef __attribute__((ext_vector_type(8))) short short8;
typedef __attribute__((ext_vector_type(4))) float f32x4;

__device__ __forceinline__ unsigned short f2bfu(float v) {
    union { float f; unsigned u; } a; a.f = v;
    unsigned r = a.u + 0x7fffu + ((a.u >> 16) & 1u);
    return (unsigned short)(r >> 16);
}
__device__ __forceinline__ float bfu2f(unsigned short h) {
    union { unsigned u; float f; } a; a.u = ((unsigned)h) << 16;
    return a.f;
}

// ---------------- 1. causal depthwise conv (W=4) + silu ----------------
__global__ __launch_bounds__(256) void k_conv(const float* __restrict__ x,
    const float* __restrict__ cw, const float* __restrict__ cb,
    float* __restrict__ shift)
{
    size_t idx = (size_t)blockIdx.x * 256 + threadIdx.x;
    int d = (int)(idx % D_);
    size_t n = idx / D_;
    int l = (int)(n % L_);
    float y = cb[d];
    const float* wp = cw + (size_t)d * 4;
#pragma unroll
    for (int i = 0; i < 4; i++) {
        int ll = l - 3 + i;
        if (ll >= 0) y = fmaf(x[idx + (size_t)(i - 3) * D_], wp[i], y);
    }
    shift[idx] = y / (1.f + expf(-y));
}

// ---------------- weight cast fp32 -> bf16 ----------------
__device__ __forceinline__ unsigned pkbf(float a, float b) {
    union { __hip_bfloat162 h; unsigned u; } cv;
    cv.h = __float22bfloat162_rn(make_float2(a, b));
    return cv.u;
}

__global__ __launch_bounds__(256) void k_castw(
    const float* __restrict__ s0, const float* __restrict__ s1,
    const float* __restrict__ s2, const float* __restrict__ s3,
    unsigned short* __restrict__ d0, unsigned short* __restrict__ d1,
    unsigned short* __restrict__ d2, unsigned short* __restrict__ d3)
{
    int which = blockIdx.x >> 8;
    int idx = ((blockIdx.x & 255) * 256 + threadIdx.x) * 4;
    const float* s = which == 0 ? s0 : which == 1 ? s1 : which == 2 ? s2 : s3;
    unsigned short* d = which == 0 ? d0 : which == 1 ? d1 : which == 2 ? d2 : d3;
    float4 v = *(const float4*)(s + idx);
    uint2 o;
    o.x = pkbf(v.x, v.y);
    o.y = pkbf(v.z, v.w);
    *(uint2*)(d + idx) = o;
}

// ---------------- bf16 MFMA NT GEMM (unchanged from R3) ----------------
__global__ __launch_bounds__(256) void k_mfma_nt(
    const float* __restrict__ A, const unsigned short* __restrict__ Bb,
    float* __restrict__ out, int K, int ldo, int jo,
    int mode, const float* __restrict__ bias, const float* __restrict__ xmul)
{
    __shared__ unsigned short As[128 * 32];
    __shared__ unsigned short Bs[128 * 32];
    int tid = threadIdx.x;
    int n0 = blockIdx.x * 128;
    int jblk = blockIdx.y * 128;
    int wave = tid >> 6, lane = tid & 63;
    int quad = lane >> 4, lcol = lane & 15;
    int wrow = (wave >> 1) * 64, wcol = (wave & 1) * 64;

    f32x4 acc[4][4];
#pragma unroll
    for (int i = 0; i < 4; i++)
#pragma unroll
        for (int j = 0; j < 4; j++) acc[i][j] = {0.f, 0.f, 0.f, 0.f};

    for (int k0 = 0; k0 < K; k0 += 32) {
        float4 a0[2][2];
        uint4 bv[2];
#pragma unroll
        for (int p = 0; p < 2; p++) {
            int idx = p * 256 + tid;
            int row = idx >> 2, sub = idx & 3;
            const float* ap = A + (size_t)(n0 + row) * K + k0 + sub * 8;
            a0[p][0] = *(const float4*)ap;
            a0[p][1] = *(const float4*)(ap + 4);
            bv[p] = *(const uint4*)(Bb + (size_t)(jblk + row) * K + k0 + sub * 8);
        }
        __syncthreads();
#pragma unroll
        for (int p = 0; p < 2; p++) {
            int idx = p * 256 + tid;
            int row = idx >> 2, sub = idx & 3;
            uint4 w;
            w.x = pkbf(a0[p][0].x, a0[p][0].y);
            w.y = pkbf(a0[p][0].z, a0[p][0].w);
            w.z = pkbf(a0[p][1].x, a0[p][1].y);
            w.w = pkbf(a0[p][1].z, a0[p][1].w);
            *(uint4*)&As[row * 32 + sub * 8] = w;
            *(uint4*)&Bs[row * 32 + sub * 8] = bv[p];
        }
        __syncthreads();
        short8 af[4], bfr[4];
#pragma unroll
        for (int i = 0; i < 4; i++)
            af[i] = *(short8*)&As[(wrow + i * 16 + lcol) * 32 + quad * 8];
#pragma unroll
        for (int j = 0; j < 4; j++)
            bfr[j] = *(short8*)&Bs[(wcol + j * 16 + lcol) * 32 + quad * 8];
#pragma unroll
        for (int i = 0; i < 4; i++)
#pragma unroll
            for (int j = 0; j < 4; j++)
                acc[i][j] = __builtin_amdgcn_mfma_f32_16x16x32_bf16(
                    af[i], bfr[j], acc[i][j], 0, 0, 0);
    }

#pragma unroll
    for (int i = 0; i < 4; i++) {
#pragma unroll
        for (int j = 0; j < 4; j++) {
#pragma unroll
            for (int q = 0; q < 4; q++) {
                int row = wrow + i * 16 + quad * 4 + q;
                int col = wcol + j * 16 + lcol;
                int n = n0 + row;
                int jc = jblk + col;
                float val = acc[i][j][q];
                if (mode == 1) {
                    val += bias[jc];
                    val = 1.f / (1.f + expf(-val));
                    val *= xmul[(size_t)n * ldo + jo + jc];
                }
                out[(size_t)n * ldo + jo + jc] = val;
            }
        }
    }
}

// ---------------- 5. per-token gate prep (Gb stores RAW g) ----------------
__global__ __launch_bounds__(64) void k_prep(const float* __restrict__ rkmg,
    const float* __restrict__ mb, float* __restrict__ Rb,
    float* __restrict__ Kb, float* __restrict__ Gb)
{
    int n = blockIdx.x;
    int m = threadIdx.x;
    const float* row = rkmg + (size_t)n * 256;
    float r   = row[m];
    float k   = row[64 + m];
    float mg1 = row[128 + m] + mb[m];
    float mg2 = row[192 + m] + mb[64 + m];
    float sel = (mg1 > 20.f) ? mg1 : log1pf(expf(mg1));
    float tau = 1.f / (1.f + expf(-mg2));
    float it  = expf(tau * logf(sel));
    float g   = -sel * tau;
    float s2  = k * k;
#pragma unroll
    for (int off = 32; off >= 1; off >>= 1) s2 += __shfl_xor(s2, off, 64);
    float kn = k / fmaxf(sqrtf(s2), 1e-12f);
    size_t o = (size_t)n * 64 + m;
    Rb[o] = r;
    Kb[o] = kn * it;
    Gb[o] = g;
}

// ---------------- 6. chunked recurrence, MFMA version ----------------
// block = (b, 32-d slice): 256 blocks x 256 thr (4 waves), 1 block/CU.
// Per chunk (C=16): decay transform -> rt/kd/kcT bf16 (K-contiguous LDS),
// wave0: P = mask(rt@kd^T) via MFMA -> LDS; waves0,1: O = P@U + rt@S (6 MFMAs,
// hi/lo split on U and S); waves2,3: S' = aC*S + kcT@U into ping-pong S.
__global__ __launch_bounds__(256) void k_chunk(
    const float* __restrict__ Rb, const float* __restrict__ Kb,
    const float* __restrict__ Gb, const float* __restrict__ u,
    const float* __restrict__ shift, const float* __restrict__ rw,
    float* __restrict__ out)
{
    __shared__ __align__(16) float rS[16 * 64];
    __shared__ __align__(16) float kS[16 * 64];
    __shared__ __align__(16) float gS[16 * 64];
    __shared__ __align__(16) float seg[4 * 64];
    __shared__ __align__(16) float aC[64];
    __shared__ __align__(16) unsigned short UTh[32 * 40];  // [d][s], K=32-pad
    __shared__ __align__(16) unsigned short UTl[32 * 40];
    __shared__ __align__(16) unsigned short rt[16 * 72];   // [t][m]
    __shared__ __align__(16) unsigned short kd[16 * 72];   // [s][m]
    __shared__ __align__(16) unsigned short kcT[64 * 40];  // [m][s], K=32-pad
    __shared__ __align__(16) unsigned short Pl[16 * 40];   // [t][s], K=32-pad
    __shared__ __align__(16) unsigned short STh[2][32 * 72]; // [d][m] ping-pong
    __shared__ __align__(16) unsigned short STl[2][32 * 72];

    int tid = threadIdx.x;
    int wave = tid >> 6, lane = tid & 63;
    int quad = lane >> 4, l15 = lane & 15;
    int b = blockIdx.x & 3, slice = blockIdx.x >> 2;
    int d0 = slice * 32;
    int sg = wave, mm = lane;

    // zero-init pads + initial state (once; pads never rewritten)
    for (int i = tid; i < 32 * 40; i += 256) { UTh[i] = 0; UTl[i] = 0; }
    for (int i = tid; i < 64 * 40; i += 256) kcT[i] = 0;
    for (int i = tid; i < 16 * 40; i += 256) Pl[i] = 0;
    for (int i = tid; i < 32 * 72; i += 256) {
        STh[0][i] = 0; STl[0][i] = 0; STh[1][i] = 0; STl[1][i] = 0;
    }

    size_t tokbase = (size_t)b * L_ * 64;
    size_t ubase = (size_t)b * L_ * D_ + d0;

    float rwv = 0.f;
    if (wave < 2) rwv = rw[d0 + wave * 16 + l15];

    // prefetch chunk 0
    float4 rv = *(const float4*)(Rb + tokbase + (size_t)tid * 4);
    float4 kv = *(const float4*)(Kb + tokbase + (size_t)tid * 4);
    float4 gv = *(const float4*)(Gb + tokbase + (size_t)tid * 4);
    float uv0 = u[ubase + (size_t)(tid >> 5) * D_ + (tid & 31)];
    float uv1 = u[ubase + (size_t)(8 + (tid >> 5)) * D_ + (tid & 31)];

    __syncthreads();   // zero-init visible before any staged writes/reads

    for (int c = 0; c < NCH; c++) {
        int ping = c & 1;
        int t0 = c * C_;

        // ---- stage chunk data -> LDS ----
        *(float4*)&rS[tid * 4] = rv;
        *(float4*)&kS[tid * 4] = kv;
        *(float4*)&gS[tid * 4] = gv;
        {
            int tt = tid >> 5, dd = tid & 31;
            unsigned short h0 = f2bfu(uv0);
            UTh[dd * 40 + tt] = h0;
            UTl[dd * 40 + tt] = f2bfu(uv0 - bfu2f(h0));
            unsigned short h1 = f2bfu(uv1);
            UTh[dd * 40 + 8 + tt] = h1;
            UTl[dd * 40 + 8 + tt] = f2bfu(uv1 - bfu2f(h1));
        }
        __syncthreads();   // sync1

        // prefetch next chunk (drains during decay/MFMA phases)
        if (c + 1 < NCH) {
            size_t g0 = tokbase + (size_t)(t0 + C_) * 64 + (size_t)tid * 4;
            rv = *(const float4*)(Rb + g0);
            kv = *(const float4*)(Kb + g0);
            gv = *(const float4*)(Gb + g0);
            uv0 = u[ubase + (size_t)(t0 + C_ + (tid >> 5)) * D_ + (tid & 31)];
            uv1 = u[ubase + (size_t)(t0 + C_ + 8 + (tid >> 5)) * D_ + (tid & 31)];
        }

        // ---- decay transform ----
        {
            float g0v = gS[(sg * 4 + 0) * 64 + mm];
            float g1v = gS[(sg * 4 + 1) * 64 + mm];
            float g2v = gS[(sg * 4 + 2) * 64 + mm];
            float g3v = gS[(sg * 4 + 3) * 64 + mm];
            float c0 = g0v, c1 = c0 + g1v, c2 = c1 + g2v, c3 = c2 + g3v;
            seg[sg * 64 + mm] = c3;
            __syncthreads();   // sync2
            float off = 0.f, tot = 0.f;
#pragma unroll
            for (int s = 0; s < 4; s++) {
                float v = seg[s * 64 + mm];
                if (s < sg) off += v;
                tot += v;
            }
            float lam[4] = {off + c0, off + c1, off + c2, off + c3};
            int i0 = sg * 4;
            ushort4 kc4;
            unsigned short kcp[4];
#pragma unroll
            for (int j = 0; j < 4; j++) {
                float rr = rS[(i0 + j) * 64 + mm];
                float kk = kS[(i0 + j) * 64 + mm];
                rt[(i0 + j) * 72 + mm] = f2bfu(rr * expf(lam[j]));
                kd[(i0 + j) * 72 + mm] = f2bfu(kk * expf(-lam[j]));
                kcp[j] = f2bfu(kk * expf(tot - lam[j]));
            }
            kc4.x = kcp[0]; kc4.y = kcp[1]; kc4.z = kcp[2]; kc4.w = kcp[3];
            *(ushort4*)&kcT[mm * 40 + i0] = kc4;
            if (sg == 0) aC[mm] = expf(tot);
        }
        __syncthreads();   // sync3

        // ---- phase A: P = mask(rt @ kd^T), wave0 only ----
        short8 af0, af1;
        if (wave < 2) {
            af0 = *(const short8*)&rt[l15 * 72 + quad * 8];
            af1 = *(const short8*)&rt[l15 * 72 + 32 + quad * 8];
        }
        if (wave == 0) {
            short8 b0 = *(const short8*)&kd[l15 * 72 + quad * 8];
            short8 b1 = *(const short8*)&kd[l15 * 72 + 32 + quad * 8];
            f32x4 p = {0.f, 0.f, 0.f, 0.f};
            p = __builtin_amdgcn_mfma_f32_16x16x32_bf16(af0, b0, p, 0, 0, 0);
            p = __builtin_amdgcn_mfma_f32_16x16x32_bf16(af1, b1, p, 0, 0, 0);
#pragma unroll
            for (int q = 0; q < 4; q++) {
                int t = quad * 4 + q;
                float v = (l15 <= t) ? p[q] : 0.f;
                Pl[t * 40 + l15] = f2bfu(v);
            }
        }
        __syncthreads();   // sync4

        // ---- phase B ----
        if (wave < 2) {
            // O = SCALE*(P@U + rt@S) + shift*rw for d-half h
            int h = wave;
            short8 pA = *(const short8*)&Pl[l15 * 40 + quad * 8];
            short8 uh = *(const short8*)&UTh[(h * 16 + l15) * 40 + quad * 8];
            short8 ul = *(const short8*)&UTl[(h * 16 + l15) * 40 + quad * 8];
            const unsigned short* sbh = &STh[ping][(h * 16 + l15) * 72];
            const unsigned short* sbl = &STl[ping][(h * 16 + l15) * 72];
            short8 sh0 = *(const short8*)&sbh[quad * 8];
            short8 sh1 = *(const short8*)&sbh[32 + quad * 8];
            short8 sl0 = *(const short8*)&sbl[quad * 8];
            short8 sl1 = *(const short8*)&sbl[32 + quad * 8];
            f32x4 o = {0.f, 0.f, 0.f, 0.f};
            o = __builtin_amdgcn_mfma_f32_16x16x32_bf16(pA, uh, o, 0, 0, 0);
            o = __builtin_amdgcn_mfma_f32_16x16x32_bf16(pA, ul, o, 0, 0, 0);
            o = __builtin_amdgcn_mfma_f32_16x16x32_bf16(af0, sh0, o, 0, 0, 0);
            o = __builtin_amdgcn_mfma_f32_16x16x32_bf16(af1, sh1, o, 0, 0, 0);
            o = __builtin_amdgcn_mfma_f32_16x16x32_bf16(af0, sl0, o, 0, 0, 0);
            o = __builtin_amdgcn_mfma_f32_16x16x32_bf16(af1, sl1, o, 0, 0, 0);
#pragma unroll
            for (int q = 0; q < 4; q++) {
                size_t oa = ubase + (size_t)(t0 + quad * 4 + q) * D_
                          + h * 16 + l15;
                out[oa] = SCALE_ * o[q] + shift[oa] * rwv;
            }
        } else {
            // S' = aC*S + kcT@U for d-half h (written to pong)
            int h = wave - 2;
            short8 uh = *(const short8*)&UTh[(h * 16 + l15) * 40 + quad * 8];
            short8 ul = *(const short8*)&UTl[(h * 16 + l15) * 40 + quad * 8];
#pragma unroll
            for (int mt = 0; mt < 4; mt++) {
                int sidx = (h * 16 + l15) * 72 + mt * 16 + quad * 4;
                ushort4 ch = *(const ushort4*)&STh[ping][sidx];
                ushort4 cl = *(const ushort4*)&STl[ping][sidx];
                f32x4 a4 = *(const f32x4*)&aC[mt * 16 + quad * 4];
                f32x4 sacc;
                sacc[0] = (bfu2f(ch.x) + bfu2f(cl.x)) * a4[0];
                sacc[1] = (bfu2f(ch.y) + bfu2f(cl.y)) * a4[1];
                sacc[2] = (bfu2f(ch.z) + bfu2f(cl.z)) * a4[2];
                sacc[3] = (bfu2f(ch.w) + bfu2f(cl.w)) * a4[3];
                short8 ka = *(const short8*)&kcT[(mt * 16 + l15) * 40 + quad * 8];
                sacc = __builtin_amdgcn_mfma_f32_16x16x32_bf16(ka, uh, sacc, 0, 0, 0);
                sacc = __builtin_amdgcn_mfma_f32_16x16x32_bf16(ka, ul, sacc, 0, 0, 0);
                ushort4 nh, nl;
                unsigned short hq;
                hq = f2bfu(sacc[0]); nh.x = hq; nl.x = f2bfu(sacc[0] - bfu2f(hq));
                hq = f2bfu(sacc[1]); nh.y = hq; nl.y = f2bfu(sacc[1] - bfu2f(hq));
                hq = f2bfu(sacc[2]); nh.z = hq; nl.z = f2bfu(sacc[2] - bfu2f(hq));
                hq = f2bfu(sacc[3]); nh.w = hq; nl.w = f2bfu(sacc[3] - bfu2f(hq));
                *(ushort4*)&STh[ping ^ 1][sidx] = nh;
                *(ushort4*)&STl[ping ^ 1][sidx] = nl;
            }
        }
        __syncthreads();   // sync5 (pong complete before next chunk reads)
    }
}

// ---------------- launcher ----------------
extern "C" void kernel_launch(void* const* d_in, const int* in_sizes, int n_in,
                              void* d_out, int out_size, void* d_ws, size_t ws_size,
                              hipStream_t stream)
{
    const float* x   = (const float*)d_in[0];
    const float* cw  = (const float*)d_in[1];
    const float* cb  = (const float*)d_in[2];
    const float* ipw = (const float*)d_in[3];
    const float* w0  = (const float*)d_in[4];
    const float* w1  = (const float*)d_in[5];
    const float* b1  = (const float*)d_in[6];
    const float* mw  = (const float*)d_in[7];
    const float* mb  = (const float*)d_in[8];
    const float* rw  = (const float*)d_in[9];
    float* out = (float*)d_out;

    float* ws    = (float*)d_ws;
    float* shift = ws;
    float* u     = shift + (size_t)NTOK * D_;
    float* rkmg  = u + (size_t)NTOK * D_;
    float* t1    = rkmg + (size_t)NTOK * 256;
    float* Rb    = t1 + (size_t)NTOK * R_;
    float* Kb    = Rb + (size_t)NTOK * 64;
    float* Gb    = Kb + (size_t)NTOK * 64;
    unsigned short* Wcatb = (unsigned short*)(Gb + (size_t)NTOK * 64);
    unsigned short* w0b   = Wcatb + 256 * 2048;
    unsigned short* w1b   = w0b + 128 * 2048;

    k_conv<<<(NTOK * (size_t)D_) / 256, 256, 0, stream>>>(x, cw, cb, shift);

    k_castw<<<1024, 256, 0, stream>>>(ipw, mw, w0, w1,
                                      Wcatb, Wcatb + 128 * 2048, w0b, w1b);

    k_mfma_nt<<<dim3(64, 2), 256, 0, stream>>>(shift, Wcatb, rkmg, D_, 256, 0,
                                               0, nullptr, nullptr);
    k_mfma_nt<<<dim3(64, 1), 256, 0, stream>>>(x, w0b, t1, D_, R_, 0,
                                               0, nullptr, nullptr);
    k_mfma_nt<<<dim3(64, 16), 256, 0, stream>>>(t1, w1b, u, R_, D_, 0,
                                                1, b1, x);

    k_prep<<<NTOK, 64, 0, stream>>>(rkmg, mb, Rb, Kb, Gb);

    k_chunk<<<256, 256, 0, stream>>>(Rb, Kb, Gb, u, shift, rw, out);
}